// Round 1
// baseline (865.379 us; speedup 1.0000x reference)
//
#include <hip/hip_runtime.h>
#include <stdint.h>

// ---------------------------------------------------------------------------
// SelfAttention (B=4, C=512, N=4096, A=512), softmax over QUERY axis.
// Pipeline (all GEMMs are NT: C[i][j] = sum_k A[i][k]*B[j][k], bf16 MFMA):
//   0. split weights into bf16 hi/lo; transpose+split x -> xT[n][c] hi/lo
//   1. projQK (x3 precision): QK[b][n][0:512]=Q, [512:1024]=K2[m][a]
//   2. projV  (x1):           Vt[b][c][m]
//   per batch b:
//   3. scores (x3): S_T[n][m] = sum_a Q[n][a] K2[m][a]   (fp32, 67 MB)
//   4. column softmax over n: online max/sum (2 kernels) + normalize -> P bf16
//   5. gemm3 (x1): out[n][c] = sum_m P[n][m] Vt[c][m]; epilogue fuses
//      d_out.flat = x.flat + 0.1*acc  (the torch .view makes this flat-aligned)
// ---------------------------------------------------------------------------

#define BM 128
#define BN 128
#define BK 32
#define LDT 40  // padded LDS row length (elements); 80 B rows -> 16B aligned, ~conflict-free

typedef __attribute__((ext_vector_type(8))) __bf16 bf16x8;
typedef __attribute__((ext_vector_type(4))) float f32x4;

__device__ __forceinline__ uint16_t f2bf(float f) {
  uint32_t u = __float_as_uint(f);
  u += 0x7FFFu + ((u >> 16) & 1u);  // RTNE
  return (uint16_t)(u >> 16);
}
__device__ __forceinline__ float bf2f(uint16_t h) {
  return __uint_as_float(((uint32_t)h) << 16);
}

// EPI: 0 = store fp32 (scores)
//      1 = store bf16 hi/lo + bias[j] (proj QK; bias0=bq for j<512, bias1=bk)
//      2 = store bf16 + bias[i] (proj V; bias0=bv indexed by row)
//      3 = outF[o] = xadd[o] + alpha*acc (final)
template <bool TRIPLE, int EPI>
__global__ void __launch_bounds__(256, 2) gemm_nt(
    const uint16_t* __restrict__ Ah, const uint16_t* __restrict__ Al, int lda, long zsa,
    const uint16_t* __restrict__ Bh, const uint16_t* __restrict__ Bl, int ldb, long zsb,
    int K,
    float* __restrict__ outF, uint16_t* __restrict__ outH, uint16_t* __restrict__ outL,
    int ldc, long zso,
    const float* __restrict__ bias0, const float* __restrict__ bias1,
    const float* __restrict__ xadd, float alpha)
{
  __shared__ uint16_t sAh[BM * LDT];
  __shared__ uint16_t sBh[BN * LDT];
  __shared__ uint16_t sAl[TRIPLE ? BM * LDT : 2];
  __shared__ uint16_t sBl[TRIPLE ? BN * LDT : 2];

  const int z = blockIdx.z;
  const long i0 = (long)blockIdx.x * BM;
  const long j0 = (long)blockIdx.y * BN;
  const int t = (int)threadIdx.x;
  const int lane = t & 63;
  const int wv = t >> 6;
  const int quad = lane >> 4;
  const int lrow = lane & 15;
  const int wm = (wv & 1) << 6;   // wave row quadrant
  const int wn = (wv >> 1) << 6;  // wave col quadrant

  // staging: 128 rows x 32 elems per tile; thread t covers rows r0 and r0+64, seg s0
  const int r0 = t >> 2;
  const int r1 = r0 + 64;
  const int s0 = (t & 3) << 3;

  const uint16_t* gAh0 = Ah + z * zsa + (i0 + r0) * lda + s0;
  const uint16_t* gAh1 = gAh0 + 64L * lda;
  const uint16_t* gBh0 = Bh + z * zsb + (j0 + r0) * ldb + s0;
  const uint16_t* gBh1 = gBh0 + 64L * ldb;
  const uint16_t* gAl0 = nullptr; const uint16_t* gAl1 = nullptr;
  const uint16_t* gBl0 = nullptr; const uint16_t* gBl1 = nullptr;
  if constexpr (TRIPLE) {
    gAl0 = Al + z * zsa + (i0 + r0) * lda + s0;
    gAl1 = gAl0 + 64L * lda;
    gBl0 = Bl + z * zsb + (j0 + r0) * ldb + s0;
    gBl1 = gBl0 + 64L * ldb;
  }
  const int la0 = r0 * LDT + s0;
  const int la1 = r1 * LDT + s0;

  f32x4 acc[4][4];
  const f32x4 fz = {0.f, 0.f, 0.f, 0.f};
#pragma unroll
  for (int a = 0; a < 4; a++)
#pragma unroll
    for (int b = 0; b < 4; b++) acc[a][b] = fz;

  for (int kk = 0; kk < K; kk += BK) {
    uint4 va0 = *(const uint4*)(gAh0 + kk);
    uint4 va1 = *(const uint4*)(gAh1 + kk);
    uint4 vb0 = *(const uint4*)(gBh0 + kk);
    uint4 vb1 = *(const uint4*)(gBh1 + kk);
    uint4 vc0, vc1, vd0, vd1;
    if constexpr (TRIPLE) {
      vc0 = *(const uint4*)(gAl0 + kk);
      vc1 = *(const uint4*)(gAl1 + kk);
      vd0 = *(const uint4*)(gBl0 + kk);
      vd1 = *(const uint4*)(gBl1 + kk);
    }
    __syncthreads();
    *(uint4*)&sAh[la0] = va0;
    *(uint4*)&sAh[la1] = va1;
    *(uint4*)&sBh[la0] = vb0;
    *(uint4*)&sBh[la1] = vb1;
    if constexpr (TRIPLE) {
      *(uint4*)&sAl[la0] = vc0;
      *(uint4*)&sAl[la1] = vc1;
      *(uint4*)&sBl[la0] = vd0;
      *(uint4*)&sBl[la1] = vd1;
    }
    __syncthreads();

    bf16x8 fa[4], fb[4], fal[4], fbl[4];
#pragma unroll
    for (int f = 0; f < 4; f++) {
      fa[f] = *(const bf16x8*)&sAh[(wm + f * 16 + lrow) * LDT + quad * 8];
      fb[f] = *(const bf16x8*)&sBh[(wn + f * 16 + lrow) * LDT + quad * 8];
      if constexpr (TRIPLE) {
        fal[f] = *(const bf16x8*)&sAl[(wm + f * 16 + lrow) * LDT + quad * 8];
        fbl[f] = *(const bf16x8*)&sBl[(wn + f * 16 + lrow) * LDT + quad * 8];
      }
    }
#pragma unroll
    for (int fm = 0; fm < 4; fm++)
#pragma unroll
      for (int fn = 0; fn < 4; fn++) {
        acc[fm][fn] = __builtin_amdgcn_mfma_f32_16x16x32_bf16(fa[fm], fb[fn], acc[fm][fn], 0, 0, 0);
        if constexpr (TRIPLE) {
          acc[fm][fn] = __builtin_amdgcn_mfma_f32_16x16x32_bf16(fal[fm], fb[fn], acc[fm][fn], 0, 0, 0);
          acc[fm][fn] = __builtin_amdgcn_mfma_f32_16x16x32_bf16(fa[fm], fbl[fn], acc[fm][fn], 0, 0, 0);
        }
      }
  }

  // epilogue: D frag -> col(j) = lane&15, row(i) = quad*4 + reg  [m89-verified]
  const long obase = (long)z * zso;
#pragma unroll
  for (int fm = 0; fm < 4; fm++) {
    const long gi0 = i0 + wm + fm * 16 + quad * 4;
#pragma unroll
    for (int fn = 0; fn < 4; fn++) {
      const long gj = j0 + wn + fn * 16 + lrow;
      float badd = 0.f;
      if constexpr (EPI == 1) badd = (gj < 512) ? bias0[gj] : bias1[gj - 512];
#pragma unroll
      for (int r = 0; r < 4; r++) {
        const long o = obase + (gi0 + r) * ldc + gj;
        float v = acc[fm][fn][r];
        if constexpr (EPI == 0) {
          outF[o] = v;
        } else if constexpr (EPI == 1) {
          v += badd;
          uint16_t h = f2bf(v);
          outH[o] = h;
          outL[o] = f2bf(v - bf2f(h));
        } else if constexpr (EPI == 2) {
          v += bias0[gi0 + r];
          outH[o] = f2bf(v);
        } else {
          outF[o] = fmaf(alpha, v, xadd[o]);
        }
      }
    }
  }
}

// x [b][c][n] fp32 -> xT [b][n][c] bf16 hi/lo
__global__ void transpose_split_x(const float* __restrict__ x,
                                  uint16_t* __restrict__ xh, uint16_t* __restrict__ xl)
{
  __shared__ float tile[32][33];
  const int b = blockIdx.z;
  const int n0 = blockIdx.x * 32;
  const int c0 = blockIdx.y * 32;
  const int tx = threadIdx.x;  // 0..31
  const int ty = threadIdx.y;  // 0..7
  const float* xb = x + (long)b * (512L * 4096);
#pragma unroll
  for (int k = 0; k < 4; k++) {
    int c = c0 + ty + k * 8;
    tile[ty + k * 8][tx] = xb[(long)c * 4096 + n0 + tx];
  }
  __syncthreads();
  uint16_t* xhb = xh + (long)b * (4096L * 512);
  uint16_t* xlb = xl + (long)b * (4096L * 512);
#pragma unroll
  for (int k = 0; k < 4; k++) {
    int n = n0 + ty + k * 8;
    float v = tile[tx][ty + k * 8];
    uint16_t h = f2bf(v);
    long o = (long)n * 512 + c0 + tx;
    xhb[o] = h;
    xlb[o] = f2bf(v - bf2f(h));
  }
}

// Wq,Wk -> WQK hi/lo (rows 0..511 = Wq, 512..1023 = Wk); Wv -> bf16 hi only
__global__ void split_weights(const float* __restrict__ Wq, const float* __restrict__ Wk,
                              const float* __restrict__ Wv,
                              uint16_t* __restrict__ WQKh, uint16_t* __restrict__ WQKl,
                              uint16_t* __restrict__ Wvh)
{
  int idx = blockIdx.x * 256 + threadIdx.x;  // 0 .. 786431
  if (idx < 524288) {
    float v = (idx < 262144) ? Wq[idx] : Wk[idx - 262144];
    uint16_t h = f2bf(v);
    WQKh[idx] = h;
    WQKl[idx] = f2bf(v - bf2f(h));
  } else {
    Wvh[idx - 524288] = f2bf(Wv[idx - 524288]);
  }
}

// online column max/sum over n for S[n][m]; grid (16 nchunks, 64 mstrips), 256 thr
__global__ void softmax_stats_partial(const float* __restrict__ S,
                                      float* __restrict__ pmax, float* __restrict__ psum)
{
  const int t = threadIdx.x;
  const int tm = t & 63;
  const int rg = t >> 6;
  const int m = blockIdx.y * 64 + tm;
  const int nbase = blockIdx.x * 256 + rg;
  const float* p = S + (long)nbase * 4096 + m;
  float mx = -3.4e38f, sm = 0.f;
#pragma unroll 4
  for (int i = 0; i < 64; i++) {
    float s = p[(long)i * 4 * 4096];
    float nm = fmaxf(mx, s);
    sm = sm * __expf(mx - nm) + __expf(s - nm);
    mx = nm;
  }
  __shared__ float smx[256], ssm[256];
  smx[t] = mx;
  ssm[t] = sm;
  __syncthreads();
  if (t < 64) {
    float M = smx[t], Ss = ssm[t];
    for (int g = 1; g < 4; g++) {
      float m2 = smx[g * 64 + t], s2 = ssm[g * 64 + t];
      float nm = fmaxf(M, m2);
      Ss = Ss * __expf(M - nm) + s2 * __expf(m2 - nm);
      M = nm;
    }
    int mm = blockIdx.y * 64 + t;
    pmax[blockIdx.x * 4096 + mm] = M;
    psum[blockIdx.x * 4096 + mm] = Ss;
  }
}

__global__ void softmax_stats_final(const float* __restrict__ pmax, const float* __restrict__ psum,
                                    float* __restrict__ cmax, float* __restrict__ crinv)
{
  const int m = blockIdx.x * 256 + threadIdx.x;  // grid 16
  float M = -3.4e38f, S = 0.f;
  for (int i = 0; i < 16; i++) {
    float m2 = pmax[i * 4096 + m], s2 = psum[i * 4096 + m];
    float nm = fmaxf(M, m2);
    S = S * __expf(M - nm) + s2 * __expf(m2 - nm);
    M = nm;
  }
  cmax[m] = M;
  crinv[m] = 1.f / S;
}

// P[n][m] = bf16( exp(S[n][m]-cmax[m]) * crinv[m] ); float4/ushort4 vectorized
__global__ void softmax_normalize(const float* __restrict__ S, const float* __restrict__ cmax,
                                  const float* __restrict__ crinv, uint16_t* __restrict__ P)
{
  const long i4 = (long)blockIdx.x * 256 + threadIdx.x;  // grid 16384 -> 4,194,304 float4s
  const float4 s4 = ((const float4*)S)[i4];
  const int g = (int)(i4 & 1023);  // column group: m = 4*g .. 4*g+3
  const float4 cm = ((const float4*)cmax)[g];
  const float4 cr = ((const float4*)crinv)[g];
  ushort4 o;
  o.x = f2bf(__expf(s4.x - cm.x) * cr.x);
  o.y = f2bf(__expf(s4.y - cm.y) * cr.y);
  o.z = f2bf(__expf(s4.z - cm.z) * cr.z);
  o.w = f2bf(__expf(s4.w - cm.w) * cr.w);
  ((ushort4*)P)[i4] = o;
}

extern "C" void kernel_launch(void* const* d_in, const int* in_sizes, int n_in,
                              void* d_out, int out_size, void* d_ws, size_t ws_size,
                              hipStream_t stream)
{
  const float* x  = (const float*)d_in[0];
  const float* Wq = (const float*)d_in[1];
  const float* bq = (const float*)d_in[2];
  const float* Wk = (const float*)d_in[3];
  const float* bk = (const float*)d_in[4];
  const float* Wv = (const float*)d_in[5];
  const float* bv = (const float*)d_in[6];
  float* out = (float*)d_out;

  char* w = (char*)d_ws;
  uint16_t* WQKh  = (uint16_t*)(w + 0);          // 1,048,576 B
  uint16_t* WQKl  = (uint16_t*)(w + 1048576);    // 1,048,576
  uint16_t* Wvh   = (uint16_t*)(w + 2097152);    //   524,288
  uint16_t* xTh   = (uint16_t*)(w + 2621440);    // 16,777,216
  uint16_t* xTl   = (uint16_t*)(w + 19398656);   // 16,777,216
  uint16_t* QKh   = (uint16_t*)(w + 36175872);   // 33,554,432
  uint16_t* QKl   = (uint16_t*)(w + 69730304);   // 33,554,432
  uint16_t* Vt    = (uint16_t*)(w + 103284736);  // 16,777,216
  float*    S     = (float*)   (w + 120061952);  // 67,108,864 (per-batch reuse)
  uint16_t* P     = (uint16_t*)(w + 187170816);  // 33,554,432 (per-batch reuse)
  float*    pmax  = (float*)   (w + 220725248);  //    262,144
  float*    psum  = (float*)   (w + 220987392);  //    262,144
  float*    cmax  = (float*)   (w + 221249536);  //     16,384
  float*    crinv = (float*)   (w + 221265920);  //     16,384
  // total ~211 MB

  split_weights<<<3072, 256, 0, stream>>>(Wq, Wk, Wv, WQKh, WQKl, Wvh);
  transpose_split_x<<<dim3(128, 16, 4), dim3(32, 8), 0, stream>>>(x, xTh, xTl);

  // Q,K projection: QK[b][n][j], j<512 -> Q (+bq), j>=512 -> K2 (+bk); x3 precision
  gemm_nt<true, 1><<<dim3(32, 8, 4), 256, 0, stream>>>(
      xTh, xTl, 512, 2097152L, WQKh, WQKl, 512, 0L, 512,
      nullptr, QKh, QKl, 1024, 4194304L, bq, bk, nullptr, 0.f);
  // V projection: Vt[b][c][m] (+bv on row c); x1 precision
  gemm_nt<false, 2><<<dim3(4, 32, 4), 256, 0, stream>>>(
      Wvh, nullptr, 512, 0L, xTh, nullptr, 512, 2097152L, 512,
      nullptr, Vt, nullptr, 4096, 2097152L, bv, nullptr, nullptr, 0.f);

  for (int b = 0; b < 4; b++) {
    const uint16_t* Qh = QKh + (long)b * 4194304;
    const uint16_t* Ql = QKl + (long)b * 4194304;
    // S_T[n][m] = sum_a Q[n][a] * K2[m][a]; x3 precision
    gemm_nt<true, 0><<<dim3(32, 32, 1), 256, 0, stream>>>(
        Qh, Ql, 1024, 0L, Qh + 512, Ql + 512, 1024, 0L, 512,
        S, nullptr, nullptr, 4096, 0L, nullptr, nullptr, nullptr, 0.f);
    softmax_stats_partial<<<dim3(16, 64), 256, 0, stream>>>(S, pmax, psum);
    softmax_stats_final<<<16, 256, 0, stream>>>(pmax, psum, cmax, crinv);
    softmax_normalize<<<16384, 256, 0, stream>>>(S, cmax, crinv, P);
    // out[n][c] = x.flat + 0.1 * sum_m P[n][m] * Vt[c][m]
    gemm_nt<false, 3><<<dim3(32, 4, 1), 256, 0, stream>>>(
        P, nullptr, 4096, 0L, Vt + (long)b * 2097152, nullptr, 4096, 0L, 4096,
        out + (long)b * 2097152, nullptr, nullptr, 512, 0L,
        nullptr, nullptr, x + (long)b * 2097152, 0.1f);
  }
}

// Round 3
// 367.939 us; speedup vs baseline: 2.3520x; 2.3520x over previous
//
#include <hip/hip_runtime.h>
#include <stdint.h>

// ---------------------------------------------------------------------------
// SelfAttention (B=4, C=512, N=4096, A=512), softmax over QUERY axis (n).
// All-fp16 MFMA pipeline, z-batched over B=4:
//   prep:   weights -> fp16; x[b][c][n] -> xT[b][n][c] fp16
//   projQK: QK[z][n][0:512]=Q+bq, [512:1024]=K+bk          (fp16)
//   projV:  Vt[z][c][m] = Wv·x + bv                         (fp16)
//   scores: per 128x128 tile of S[n][m]=Q·K^T: compute per-column (m)
//           tile max & sumexp -> pmax/psum[z][32][4096]; store
//           S~[z][n][m] = fp16 exp(s - tile_max)
//   stats_final: lse[z][m] = M + log(sum) over 32 tiles
//   scale_factors: fscale[z][tile][m] = exp(pmax - lse)
//   gemm3:  out[z][n][c] = x.flat + 0.1 * sum_m (S~ * fscale)[n][m] Vt[c][m]
//           (torch .view makes the residual flat-aligned)
// ---------------------------------------------------------------------------

#define LDT 40  // padded LDS row (f16 elems); 80B rows

typedef _Float16 f16x8 __attribute__((ext_vector_type(8)));
typedef float f32x4 __attribute__((ext_vector_type(4)));

// ASRC: 0 = A is fp16; 1 = A is fp16 S~ scaled by fscale[z][i0>>7][m] (via `lse` arg)
// EPI:  1 = fp16 out + bias by col (bias0 for j<512, bias1 else)   [projQK]
//       2 = fp16 out + bias by row (bias0)                          [projV]
//       3 = fp32 out = xadd[o] + alpha*acc                          [gemm3]
//       4 = fused scores: tile stats -> pmax/psum, S~ fp16 out      [scores]
template <int ASRC, int EPI>
__global__ void __launch_bounds__(256, 2) gemm_f16(
    const void* __restrict__ Ap, long lda, long zsa,
    const _Float16* __restrict__ Bp, long ldb, long zsb,
    int kslice,
    const float* __restrict__ lse, long zsl,
    float* __restrict__ outF, _Float16* __restrict__ outH, long ldc, long zso,
    const float* __restrict__ bias0, const float* __restrict__ bias1,
    const float* __restrict__ xadd,
    float* __restrict__ pmax, float* __restrict__ psum, long zsp,
    float alpha)
{
  __shared__ _Float16 sA[128 * LDT];
  __shared__ _Float16 sB[128 * LDT];

  const int z = blockIdx.z;
  const long i0 = (long)blockIdx.x * 128;
  const long j0 = (long)blockIdx.y * 128;
  const int t = (int)threadIdx.x;
  const int lane = t & 63;
  const int wv = t >> 6;
  const int quad = lane >> 4;
  const int lrow = lane & 15;
  const int wm = (wv & 1) << 6;
  const int wn = (wv >> 1) << 6;
  const int r0 = t >> 2;
  const int s0 = (t & 3) << 3;

  const _Float16* gB0 = Bp + z * zsb + (j0 + r0) * ldb + s0;
  const _Float16* gB1 = gB0 + 64 * ldb;
  const int la0 = r0 * LDT + s0;
  const int la1 = (r0 + 64) * LDT + s0;

  const _Float16* gA0 = nullptr;
  const _Float16* gA1 = nullptr;
  const float* fsZ = nullptr;
  gA0 = (const _Float16*)Ap + z * zsa + (i0 + r0) * lda + s0;
  gA1 = gA0 + 64 * lda;
  if constexpr (ASRC == 1) {
    fsZ = lse + z * zsl + (long)blockIdx.x * 4096 + s0;  // fscale row for this n-tile
  }

  f32x4 acc[4][4];
  const f32x4 fz = {0.f, 0.f, 0.f, 0.f};
#pragma unroll
  for (int a = 0; a < 4; a++)
#pragma unroll
    for (int b = 0; b < 4; b++) acc[a][b] = fz;

  for (int kk = 0; kk < kslice; kk += 32) {
    f16x8 a0 = *(const f16x8*)(gA0 + kk);
    f16x8 a1 = *(const f16x8*)(gA1 + kk);
    f16x8 b0 = *(const f16x8*)(gB0 + kk);
    f16x8 b1 = *(const f16x8*)(gB1 + kk);
    if constexpr (ASRC == 1) {
      float4 f0 = *(const float4*)(fsZ + kk);
      float4 f1 = *(const float4*)(fsZ + kk + 4);
      f16x8 fv;
      fv[0] = (_Float16)f0.x; fv[1] = (_Float16)f0.y;
      fv[2] = (_Float16)f0.z; fv[3] = (_Float16)f0.w;
      fv[4] = (_Float16)f1.x; fv[5] = (_Float16)f1.y;
      fv[6] = (_Float16)f1.z; fv[7] = (_Float16)f1.w;
      a0 = a0 * fv;
      a1 = a1 * fv;
    }
    __syncthreads();
    *(f16x8*)&sA[la0] = a0;
    *(f16x8*)&sA[la1] = a1;
    *(f16x8*)&sB[la0] = b0;
    *(f16x8*)&sB[la1] = b1;
    __syncthreads();

    f16x8 fa[4], fb[4];
#pragma unroll
    for (int f = 0; f < 4; f++) {
      fa[f] = *(const f16x8*)&sA[(wm + f * 16 + lrow) * LDT + quad * 8];
      fb[f] = *(const f16x8*)&sB[(wn + f * 16 + lrow) * LDT + quad * 8];
    }
#pragma unroll
    for (int fm = 0; fm < 4; fm++)
#pragma unroll
      for (int fn = 0; fn < 4; fn++)
        acc[fm][fn] = __builtin_amdgcn_mfma_f32_16x16x32_f16(fa[fm], fb[fn], acc[fm][fn], 0, 0, 0);
  }

  // D frag: col(j) = lane&15 (+wn+fn*16), row(i) = quad*4 + reg (+wm+fm*16)
  const long obase = (long)z * zso;

  if constexpr (EPI == 1 || EPI == 2) {
#pragma unroll
    for (int fm = 0; fm < 4; fm++) {
      const long gi0 = i0 + wm + fm * 16 + quad * 4;
#pragma unroll
      for (int fn = 0; fn < 4; fn++) {
        const long gj = j0 + wn + fn * 16 + lrow;
        float badd = 0.f;
        if constexpr (EPI == 1) badd = (gj < 512) ? bias0[gj] : bias1[gj - 512];
#pragma unroll
        for (int r = 0; r < 4; r++) {
          float v = acc[fm][fn][r];
          if constexpr (EPI == 1) v += badd;
          else v += bias0[gi0 + r];
          outH[obase + (gi0 + r) * ldc + gj] = (_Float16)v;
        }
      }
    }
  } else if constexpr (EPI == 3) {
#pragma unroll
    for (int fm = 0; fm < 4; fm++) {
      const long gi0 = i0 + wm + fm * 16 + quad * 4;
#pragma unroll
      for (int fn = 0; fn < 4; fn++) {
        const long gj = j0 + wn + fn * 16 + lrow;
#pragma unroll
        for (int r = 0; r < 4; r++) {
          const long o = obase + (gi0 + r) * ldc + gj;
          outF[o] = fmaf(alpha, acc[fm][fn][r], xadd[o]);
        }
      }
    }
  } else {  // EPI == 4: fused scores stats + S~ store
    __syncthreads();  // done with K-loop LDS reads
    float* Ls = (float*)sA;  // 2560 floats: [0,1024) mx, [1024,2048) sm, [2048,2560) round2
    // stage 1: per-lane per-column-group stats (16 rows each)
#pragma unroll
    for (int fn = 0; fn < 4; fn++) {
      float mx = -3.4e38f;
#pragma unroll
      for (int fm = 0; fm < 4; fm++)
#pragma unroll
        for (int r = 0; r < 4; r++) mx = fmaxf(mx, acc[fm][fn][r]);
      float sm = 0.f;
#pragma unroll
      for (int fm = 0; fm < 4; fm++)
#pragma unroll
        for (int r = 0; r < 4; r++) sm += __expf(acc[fm][fn][r] - mx);
      Ls[(wv * 4 + quad) * 64 + fn * 16 + lrow] = mx;
      Ls[1024 + (wv * 4 + quad) * 64 + fn * 16 + lrow] = sm;
    }
    __syncthreads();
    // stage 2: combine 4 quads -> per (row-half h, col c)
    {
      const int c = t & 127;
      const int h = t >> 7;
      const int wvv = ((c >> 6) << 1) + h;  // wv bit0 = row half, bit1 = col half
      const int wc = c & 63;
      float M = -3.4e38f, Ss = 0.f;
#pragma unroll
      for (int q = 0; q < 4; q++) {
        float m2 = Ls[(wvv * 4 + q) * 64 + wc];
        float s2 = Ls[1024 + (wvv * 4 + q) * 64 + wc];
        float nm = fmaxf(M, m2);
        Ss = Ss * __expf(M - nm) + s2 * __expf(m2 - nm);
        M = nm;
      }
      Ls[2048 + h * 128 + c] = M;   // disjoint from stage-1/2 read region
      Ls[2304 + h * 128 + c] = Ss;
    }
    __syncthreads();
    // stage 3: combine halves -> per-column tile stats; keep Mcol in LDS
    if (t < 128) {
      float m0 = Ls[2048 + t], m1 = Ls[2048 + 128 + t];
      float sa = Ls[2304 + t], sb = Ls[2304 + 128 + t];
      float nm = fmaxf(m0, m1);
      float s = sa * __expf(m0 - nm) + sb * __expf(m1 - nm);
      const long pidx = z * zsp + (long)blockIdx.x * 4096 + j0 + t;
      pmax[pidx] = nm;
      psum[pidx] = s;
      Ls[t] = nm;
    }
    __syncthreads();
    // stage 4: store S~ = fp16 exp(acc - tile_col_max)
#pragma unroll
    for (int fn = 0; fn < 4; fn++) {
      const int colc = wn + fn * 16 + lrow;
      const float Mcol = Ls[colc];
      const long gj = j0 + colc;
#pragma unroll
      for (int fm = 0; fm < 4; fm++) {
        const long gi0 = i0 + wm + fm * 16 + quad * 4;
#pragma unroll
        for (int r = 0; r < 4; r++)
          outH[obase + (gi0 + r) * ldc + gj] = (_Float16)__expf(acc[fm][fn][r] - Mcol);
      }
    }
  }
}

__global__ void convert_weights(const float* __restrict__ Wq, const float* __restrict__ Wk,
                                const float* __restrict__ Wv,
                                _Float16* __restrict__ WQK, _Float16* __restrict__ Wv16)
{
  int idx = blockIdx.x * 256 + threadIdx.x;  // 0..786431
  if (idx < 524288)
    WQK[idx] = (_Float16)((idx < 262144) ? Wq[idx] : Wk[idx - 262144]);
  else
    Wv16[idx - 524288] = (_Float16)Wv[idx - 524288];
}

// x [b][c][n] fp32 -> xT [b][n][c] fp16
__global__ void transpose_x(const float* __restrict__ x, _Float16* __restrict__ xT)
{
  __shared__ float tile[32][33];
  const int b = blockIdx.z;
  const int n0 = blockIdx.x * 32;
  const int c0 = blockIdx.y * 32;
  const int tx = threadIdx.x;  // 0..31
  const int ty = threadIdx.y;  // 0..7
  const float* xb = x + (long)b * 2097152;
#pragma unroll
  for (int k = 0; k < 4; k++)
    tile[ty + k * 8][tx] = xb[(long)(c0 + ty + k * 8) * 4096 + n0 + tx];
  __syncthreads();
  _Float16* xTb = xT + (long)b * 2097152;
#pragma unroll
  for (int k = 0; k < 4; k++)
    xTb[(long)(n0 + ty + k * 8) * 512 + c0 + tx] = (_Float16)tile[tx][ty + k * 8];
}

// lse[z][m] = combine 32 tile partials
__global__ void stats_final(const float* __restrict__ pmax, const float* __restrict__ psum,
                            float* __restrict__ lse)
{
  const int idx = blockIdx.x * 256 + threadIdx.x;  // z*4096+m, grid 64
  const int z = idx >> 12;
  const int m = idx & 4095;
  const float* pm = pmax + (long)z * 131072 + m;
  const float* ps = psum + (long)z * 131072 + m;
  float M = -3.4e38f, S = 0.f;
  for (int i = 0; i < 32; i++) {
    float m2 = pm[(long)i * 4096], s2 = ps[(long)i * 4096];
    float nm = fmaxf(M, m2);
    S = S * __expf(M - nm) + s2 * __expf(m2 - nm);
    M = nm;
  }
  lse[idx] = M + __logf(S);
}

// fscale[z][tile][m] = exp(pmax - lse[z][m])
__global__ void scale_factors(const float* __restrict__ pmax, const float* __restrict__ lse,
                              float* __restrict__ fscale)
{
  const int idx = blockIdx.x * 256 + threadIdx.x;  // 0..524287, grid 2048
  const int z = idx >> 17;
  const int m = idx & 4095;
  fscale[idx] = __expf(pmax[idx] - lse[(z << 12) + m]);
}

extern "C" void kernel_launch(void* const* d_in, const int* in_sizes, int n_in,
                              void* d_out, int out_size, void* d_ws, size_t ws_size,
                              hipStream_t stream)
{
  const float* x  = (const float*)d_in[0];
  const float* Wq = (const float*)d_in[1];
  const float* bq = (const float*)d_in[2];
  const float* Wk = (const float*)d_in[3];
  const float* bk = (const float*)d_in[4];
  const float* Wv = (const float*)d_in[5];
  const float* bv = (const float*)d_in[6];
  float* out = (float*)d_out;

  char* w = (char*)d_ws;
  _Float16* WQK   = (_Float16*)(w + 0);          //  1,048,576
  _Float16* Wv16  = (_Float16*)(w + 1048576);    //    524,288
  _Float16* xT    = (_Float16*)(w + 1572864);    // 16,777,216
  _Float16* QK    = (_Float16*)(w + 18350080);   // 33,554,432
  _Float16* Vt    = (_Float16*)(w + 51904512);   // 16,777,216
  float*    lse   = (float*)   (w + 68681728);   //     65,536
  float*    pmaxB = (float*)   (w + 68747264);   //  2,097,152
  float*    psumB = (float*)   (w + 70844416);   //  2,097,152
  float*    fscal = (float*)   (w + 72941568);   //  2,097,152 = [z][32][4096] floats
  _Float16* S16   = (_Float16*)(w + 75038720);   // 134,217,728
  // total 209,256,448 B

  convert_weights<<<3072, 256, 0, stream>>>(Wq, Wk, Wv, WQK, Wv16);
  transpose_x<<<dim3(128, 16, 4), dim3(32, 8), 0, stream>>>(x, xT);

  // projQK: QK[z][n][j] fp16, j<512 Q(+bq), j>=512 K(+bk)
  gemm_f16<0, 1><<<dim3(32, 8, 4), 256, 0, stream>>>(
      xT, 512, 2097152L, WQK, 512, 0L, 512, nullptr, 0L,
      nullptr, QK, 1024, 4194304L, bq, bk, nullptr, nullptr, nullptr, 0L, 0.f);
  // projV: Vt[z][c][m] fp16 (+bv by row)
  gemm_f16<0, 2><<<dim3(4, 32, 4), 256, 0, stream>>>(
      Wv16, 512, 0L, xT, 512, 2097152L, 512, nullptr, 0L,
      nullptr, Vt, 4096, 2097152L, bv, nullptr, nullptr, nullptr, nullptr, 0L, 0.f);
  // scores: S~[z][n][m] fp16 + tile stats
  gemm_f16<0, 4><<<dim3(32, 32, 4), 256, 0, stream>>>(
      QK, 1024, 4194304L, QK + 512, 1024, 4194304L, 512, nullptr, 0L,
      nullptr, S16, 4096, 16777216L, nullptr, nullptr, nullptr,
      pmaxB, psumB, 131072L, 0.f);
  stats_final<<<64, 256, 0, stream>>>(pmaxB, psumB, lse);
  scale_factors<<<2048, 256, 0, stream>>>(pmaxB, lse, fscal);
  // gemm3: out = x.flat + 0.1 * (S~*fscale) · Vt^T
  // fscal z-stride = 131072 ELEMENTS ([z][32][4096]) — round-2 bug was 524288 here
  gemm_f16<1, 3><<<dim3(32, 4, 4), 256, 0, stream>>>(
      S16, 4096, 16777216L, Vt, 4096, 2097152L, 4096, fscal, 131072L,
      out, nullptr, 512, 2097152L, nullptr, nullptr, x, nullptr, nullptr, 0L, 0.1f);
}